// Round 1
// baseline (1676.198 us; speedup 1.0000x reference)
//
#include <hip/hip_runtime.h>
#include <math.h>

// ExaoneMoe: router(fp32) + grouped-topk + routed experts (bf16 MFMA) + shared expert.
// HBM floor ~192us (1.21GB fp32 expert weights, read-once). bf16 MFMA keeps compute
// under the memory floor (no fp32 MFMA on CDNA4).

#define TOK 2048
#define HD 2048
#define NE 64
#define FD 768
#define TKK 6
#define CAPE 384
#define NG 8
#define KGG 4

typedef float f32x4 __attribute__((ext_vector_type(4)));
typedef short s16x8 __attribute__((ext_vector_type(8)));
typedef short s16x4 __attribute__((ext_vector_type(4)));

__device__ __forceinline__ short f2bf(float f){
  unsigned u = __float_as_uint(f);
  u += 0x7FFFu + ((u >> 16) & 1u);   // RNE
  return (short)(u >> 16);
}

// ---------------- x fp32 -> bf16 ----------------
__global__ void k_convert(const float* __restrict__ x, short* __restrict__ xbf){
  int i = blockIdx.x * 256 + threadIdx.x;          // 1,048,576 threads x 4 elems
  f32x4 v = ((const f32x4*)x)[i];
  s16x4 o = { f2bf(v[0]), f2bf(v[1]), f2bf(v[2]), f2bf(v[3]) };
  ((s16x4*)xbf)[i] = o;
}

// ---------------- router logits (fp32, selection-critical) ----------------
__global__ void k_router(const float* __restrict__ x, const float* __restrict__ gw,
                         float* __restrict__ logits){
  const int t = blockIdx.x * 4 + (threadIdx.x >> 6);
  const int e = threadIdx.x & 63;
  const float* xr = x + (size_t)t * HD;
  float acc = 0.f;
  for (int h = 0; h < HD; h += 4){
    f32x4 xv = *(const f32x4*)(xr + h);
    acc = fmaf(xv[0], gw[(h + 0) * NE + e], acc);
    acc = fmaf(xv[1], gw[(h + 1) * NE + e], acc);
    acc = fmaf(xv[2], gw[(h + 2) * NE + e], acc);
    acc = fmaf(xv[3], gw[(h + 3) * NE + e], acc);
  }
  logits[t * NE + e] = acc;
}

// ---------------- grouped topk + binning ----------------
__global__ void k_topk(const float* __restrict__ logits, const float* __restrict__ bias,
                       int* __restrict__ cnt, int* __restrict__ tokl, float* __restrict__ wl){
  const int t = blockIdx.x * 256 + threadIdx.x;
  float sc[NE], sb[NE];
  for (int e = 0; e < NE; ++e){
    float l = logits[t * NE + e];
    float s = 1.f / (1.f + expf(-l));
    sc[e] = s; sb[e] = s + bias[e];
  }
  float gs[NG];
  for (int g = 0; g < NG; ++g){
    float m1 = -1e30f, m2 = -1e30f;
    for (int q = 0; q < 8; ++q){
      float v = sb[g * 8 + q];
      if (v > m1){ m2 = m1; m1 = v; } else if (v > m2){ m2 = v; }
    }
    gs[g] = m1 + m2;
  }
  unsigned gm = 0; unsigned long long allow = 0;
  for (int r = 0; r < KGG; ++r){
    float bb = -1e30f; int bg = 0;
    for (int g = 0; g < NG; ++g)
      if (!((gm >> g) & 1u) && gs[g] > bb){ bb = gs[g]; bg = g; }   // strict > = JAX tie-break
    gm |= 1u << bg; allow |= 0xFFull << (bg * 8);
  }
  unsigned long long used = 0; int ids[TKK]; float wv[TKK]; float wsum = 0.f;
  for (int r = 0; r < TKK; ++r){
    float bb = -1e30f; int bi = 0;
    for (int e = 0; e < NE; ++e)
      if (((allow >> e) & 1ull) && !((used >> e) & 1ull) && sb[e] > bb){ bb = sb[e]; bi = e; }
    used |= 1ull << bi; ids[r] = bi;
    float w = sc[bi]; wv[r] = w; wsum += w;     // weights from UNBIASED scores
  }
  const float scl = 2.5f / wsum;
  for (int r = 0; r < TKK; ++r){
    int e = ids[r];
    int slot = atomicAdd(cnt + e, 1);
    if (slot < CAPE){ tokl[e * CAPE + slot] = t; wl[e * CAPE + slot] = wv[r] * scl; }
  }
}

// ---------------- dual (gate||up) GEMM + silu-mul -> bf16 h ----------------
// M_tile=256 (4 waves x 64 rows), N_tile=64, BK=64, mfma 16x16x32 bf16.
template<bool GATHER>
__global__ __launch_bounds__(256, 2) void k_dual(
    const short* __restrict__ xbf,
    const float* __restrict__ Wg, const float* __restrict__ Wu,
    short* __restrict__ hout,
    const int* __restrict__ cnt, const int* __restrict__ tokl)
{
  __shared__ short Asm[256][72];   // [m][k] k-contig, +8 pad (16B) per row
  __shared__ short Bgs[64][72];    // [n][k] k-contig (transposed at staging)
  __shared__ short Bus[64][72];
  const int tid = threadIdx.x;
  const int n0 = blockIdx.x * 64;
  const int m0 = blockIdx.y * 256;
  const int e  = GATHER ? (int)blockIdx.z : 0;
  const int cntc = GATHER ? min(cnt[e], CAPE) : TOK;
  if (m0 >= cntc) return;
  const size_t wb = (size_t)e * HD * FD;
  const float* wg = Wg + wb;
  const float* wu = Wu + wb;

  const int a_r = tid >> 3, a_c = tid & 7;
  const short* arow[8];
#pragma unroll
  for (int p = 0; p < 8; ++p){
    const int gr = m0 + p * 32 + a_r;
    const short* s = nullptr;
    if (gr < cntc){
      const int row = GATHER ? tokl[e * CAPE + gr] : gr;
      s = xbf + (size_t)row * HD;
    }
    arow[p] = s;
  }
  const int b_kg = tid >> 4, b_ng = tid & 15;
  const int lane = tid & 63, wv = tid >> 6;
  const int lm = lane & 15, quad = lane >> 4;

  f32x4 ag[4][4], au[4][4];
#pragma unroll
  for (int i = 0; i < 4; ++i)
#pragma unroll
    for (int j = 0; j < 4; ++j){
      ag[i][j] = {0.f, 0.f, 0.f, 0.f};
      au[i][j] = {0.f, 0.f, 0.f, 0.f};
    }

  for (int k0 = 0; k0 < HD; k0 += 64){
    __syncthreads();
#pragma unroll
    for (int p = 0; p < 8; ++p){
      s16x8 v = {0, 0, 0, 0, 0, 0, 0, 0};
      if (arow[p]) v = *(const s16x8*)(arow[p] + k0 + a_c * 8);
      *(s16x8*)&Asm[p * 32 + a_r][a_c * 8] = v;
    }
    {
      const float* src = wg + (size_t)(k0 + b_kg * 4) * FD + n0 + b_ng * 4;
      f32x4 r0 = *(const f32x4*)(src);
      f32x4 r1 = *(const f32x4*)(src + FD);
      f32x4 r2 = *(const f32x4*)(src + 2 * FD);
      f32x4 r3 = *(const f32x4*)(src + 3 * FD);
#pragma unroll
      for (int c = 0; c < 4; ++c){
        s16x4 v = { f2bf(r0[c]), f2bf(r1[c]), f2bf(r2[c]), f2bf(r3[c]) };
        *(s16x4*)&Bgs[b_ng * 4 + c][b_kg * 4] = v;
      }
      src = wu + (size_t)(k0 + b_kg * 4) * FD + n0 + b_ng * 4;
      r0 = *(const f32x4*)(src);
      r1 = *(const f32x4*)(src + FD);
      r2 = *(const f32x4*)(src + 2 * FD);
      r3 = *(const f32x4*)(src + 3 * FD);
#pragma unroll
      for (int c = 0; c < 4; ++c){
        s16x4 v = { f2bf(r0[c]), f2bf(r1[c]), f2bf(r2[c]), f2bf(r3[c]) };
        *(s16x4*)&Bus[b_ng * 4 + c][b_kg * 4] = v;
      }
    }
    __syncthreads();
#pragma unroll
    for (int s = 0; s < 2; ++s){
      s16x8 af[4], bg[4], bu[4];
#pragma unroll
      for (int i = 0; i < 4; ++i)
        af[i] = *(const s16x8*)&Asm[wv * 64 + i * 16 + lm][s * 32 + quad * 8];
#pragma unroll
      for (int j = 0; j < 4; ++j){
        bg[j] = *(const s16x8*)&Bgs[j * 16 + lm][s * 32 + quad * 8];
        bu[j] = *(const s16x8*)&Bus[j * 16 + lm][s * 32 + quad * 8];
      }
#pragma unroll
      for (int i = 0; i < 4; ++i)
#pragma unroll
        for (int j = 0; j < 4; ++j){
          ag[i][j] = __builtin_amdgcn_mfma_f32_16x16x32_bf16(af[i], bg[j], ag[i][j], 0, 0, 0);
          au[i][j] = __builtin_amdgcn_mfma_f32_16x16x32_bf16(af[i], bu[j], au[i][j], 0, 0, 0);
        }
    }
  }
  const size_t obase = GATHER ? (size_t)e * CAPE : 0;
#pragma unroll
  for (int i = 0; i < 4; ++i){
#pragma unroll
    for (int r = 0; r < 4; ++r){
      const int grow = m0 + wv * 64 + i * 16 + quad * 4 + r;
      if (grow < cntc){
        short* orow = hout + (obase + grow) * FD + n0;
#pragma unroll
        for (int j = 0; j < 4; ++j){
          const float g = ag[i][j][r], u = au[i][j][r];
          const float h = g * u / (1.f + __expf(-g));   // silu(g)*u
          orow[j * 16 + lm] = f2bf(h);
        }
      }
    }
  }
}

// ---------------- down GEMM; SCATTER: weighted atomicAdd, else plain store ----------------
template<bool SCATTER>
__global__ __launch_bounds__(256, 2) void k_down(
    const short* __restrict__ hsrc,
    const float* __restrict__ Wd,
    float* __restrict__ out,
    const int* __restrict__ cnt, const int* __restrict__ tokl, const float* __restrict__ wl)
{
  __shared__ short Asm[256][72];
  __shared__ short Bs[64][72];
  const int tid = threadIdx.x;
  const int n0 = blockIdx.x * 64;
  const int m0 = blockIdx.y * 256;
  const int e  = SCATTER ? (int)blockIdx.z : 0;
  const int cntc = SCATTER ? min(cnt[e], CAPE) : TOK;
  if (m0 >= cntc) return;
  const short* abase = hsrc + (size_t)e * CAPE * FD;
  const float* wd = Wd + (size_t)e * FD * HD;

  const int a_r = tid >> 3, a_c = tid & 7;
  const short* arow[8];
#pragma unroll
  for (int p = 0; p < 8; ++p){
    const int gr = m0 + p * 32 + a_r;
    arow[p] = (gr < cntc) ? (abase + (size_t)gr * FD) : nullptr;
  }
  const int b_kg = tid >> 4, b_ng = tid & 15;
  const int lane = tid & 63, wv = tid >> 6;
  const int lm = lane & 15, quad = lane >> 4;

  f32x4 ac[4][4];
#pragma unroll
  for (int i = 0; i < 4; ++i)
#pragma unroll
    for (int j = 0; j < 4; ++j) ac[i][j] = {0.f, 0.f, 0.f, 0.f};

  for (int k0 = 0; k0 < FD; k0 += 64){
    __syncthreads();
#pragma unroll
    for (int p = 0; p < 8; ++p){
      s16x8 v = {0, 0, 0, 0, 0, 0, 0, 0};
      if (arow[p]) v = *(const s16x8*)(arow[p] + k0 + a_c * 8);
      *(s16x8*)&Asm[p * 32 + a_r][a_c * 8] = v;
    }
    {
      const float* src = wd + (size_t)(k0 + b_kg * 4) * HD + n0 + b_ng * 4;
      f32x4 r0 = *(const f32x4*)(src);
      f32x4 r1 = *(const f32x4*)(src + HD);
      f32x4 r2 = *(const f32x4*)(src + 2 * HD);
      f32x4 r3 = *(const f32x4*)(src + 3 * HD);
#pragma unroll
      for (int c = 0; c < 4; ++c){
        s16x4 v = { f2bf(r0[c]), f2bf(r1[c]), f2bf(r2[c]), f2bf(r3[c]) };
        *(s16x4*)&Bs[b_ng * 4 + c][b_kg * 4] = v;
      }
    }
    __syncthreads();
#pragma unroll
    for (int s = 0; s < 2; ++s){
      s16x8 af[4], bf[4];
#pragma unroll
      for (int i = 0; i < 4; ++i)
        af[i] = *(const s16x8*)&Asm[wv * 64 + i * 16 + lm][s * 32 + quad * 8];
#pragma unroll
      for (int j = 0; j < 4; ++j)
        bf[j] = *(const s16x8*)&Bs[j * 16 + lm][s * 32 + quad * 8];
#pragma unroll
      for (int i = 0; i < 4; ++i)
#pragma unroll
        for (int j = 0; j < 4; ++j)
          ac[i][j] = __builtin_amdgcn_mfma_f32_16x16x32_bf16(af[i], bf[j], ac[i][j], 0, 0, 0);
    }
  }
#pragma unroll
  for (int i = 0; i < 4; ++i){
#pragma unroll
    for (int r = 0; r < 4; ++r){
      const int grow = m0 + wv * 64 + i * 16 + quad * 4 + r;
      if (grow < cntc){
        if (SCATTER){
          const int t = tokl[e * CAPE + grow];
          const float w = wl[e * CAPE + grow];
          float* orow = out + (size_t)t * HD + n0;
#pragma unroll
          for (int j = 0; j < 4; ++j)
            atomicAdd(orow + j * 16 + lm, w * ac[i][j][r]);
        } else {
          float* orow = out + (size_t)grow * HD + n0;
#pragma unroll
          for (int j = 0; j < 4; ++j)
            orow[j * 16 + lm] = ac[i][j][r];
        }
      }
    }
  }
}

extern "C" void kernel_launch(void* const* d_in, const int* in_sizes, int n_in,
                              void* d_out, int out_size, void* d_ws, size_t ws_size,
                              hipStream_t stream){
  const float* x    = (const float*)d_in[0];
  const float* gw   = (const float*)d_in[1];
  const float* bias = (const float*)d_in[2];
  const float* wgat = (const float*)d_in[3];
  const float* wup  = (const float*)d_in[4];
  const float* wdn  = (const float*)d_in[5];
  const float* wsg  = (const float*)d_in[6];
  const float* wsu  = (const float*)d_in[7];
  const float* wsd  = (const float*)d_in[8];
  float* out = (float*)d_out;
  char* ws = (char*)d_ws;

  // ws layout (all 16B aligned), total 50,004,224 B
  short* xbf    = (short*)(ws);                      //  8,388,608
  short* hbuf   = (short*)(ws + 8388608);            // 37,748,736
  short* hs     = (short*)(ws + 46137344);           //  3,145,728
  float* logits = (float*)(ws + 49283072);           //    524,288
  int*   tokl   = (int*)  (ws + 49807360);           //     98,304
  float* wl     = (float*)(ws + 49905664);           //     98,304
  int*   cnt    = (int*)  (ws + 50003968);           //        256
  if (ws_size < 50004224) return;                    // clean wrong-answer instead of OOB

  hipMemsetAsync(cnt, 0, NE * sizeof(int), stream);
  k_convert<<<dim3(TOK * HD / 1024), 256, 0, stream>>>(x, xbf);
  k_router<<<dim3(TOK / 4), 256, 0, stream>>>(x, gw, logits);
  k_topk<<<dim3(TOK / 256), 256, 0, stream>>>(logits, bias, cnt, tokl, wl);
  // shared expert: initializes d_out fully (plain stores)
  k_dual<false><<<dim3(FD / 64, TOK / 256, 1), 256, 0, stream>>>(xbf, wsg, wsu, hs, nullptr, nullptr);
  k_down<false><<<dim3(HD / 64, TOK / 256, 1), 256, 0, stream>>>(hs, wsd, out, nullptr, nullptr, nullptr);
  // routed experts: h = silu(xWg)*xWu, then weighted atomic scatter of hWd
  k_dual<true><<<dim3(FD / 64, 2, NE), 256, 0, stream>>>(xbf, wgat, wup, hbuf, cnt, tokl);
  k_down<true><<<dim3(HD / 64, 2, NE), 256, 0, stream>>>(hbuf, wdn, out, cnt, tokl, wl);
}